// Round 2
// baseline (856.258 us; speedup 1.0000x reference)
//
#include <hip/hip_runtime.h>
#include <hip/hip_bf16.h>

typedef __attribute__((ext_vector_type(8))) short short8_t;
typedef __attribute__((ext_vector_type(4))) float f32x4_t;
typedef unsigned short u16;
typedef unsigned int u32;

#define DIV_UP(a, b) (((a) + (b) - 1) / (b))

static __device__ __forceinline__ float bflo(u32 u) { return __uint_as_float(u << 16); }
static __device__ __forceinline__ float bfhi(u32 u) { return __uint_as_float(u & 0xffff0000u); }
static __device__ __forceinline__ u32 f2bf(float f) {
  u32 u = __float_as_uint(f);
  return (u + 0x7fffu + ((u >> 16) & 1u)) >> 16;  // RTNE
}

// ---------- K1: X,H f32 -> bf16 into right halves (cols 128..255) of A matrices ----------
__global__ void k_conv_xh(const float4* __restrict__ X, const float4* __restrict__ H,
                          u32* __restrict__ Abx, u32* __restrict__ Abh, int total) {
  int t = blockIdx.x * 256 + threadIdx.x;
  if (t >= total) return;                 // total = N*32 (float4 granules)
  int nrow = t >> 5, c = t & 31;
  float4 x = X[t], h = H[t];
  uint2 px = make_uint2(f2bf(x.x) | (f2bf(x.y) << 16), f2bf(x.z) | (f2bf(x.w) << 16));
  uint2 ph = make_uint2(f2bf(h.x) | (f2bf(h.y) << 16), f2bf(h.z) | (f2bf(h.w) << 16));
  ((uint2*)(Abx + (size_t)nrow * 128 + 64))[c] = px;   // A row = 256 bf16 = 128 dwords
  ((uint2*)(Abh + (size_t)nrow * 128 + 64))[c] = ph;
}

// ---------- K2: degree histogram ----------
__global__ void k_hist(const int* __restrict__ dst, int* __restrict__ deg, int E) {
  int e = blockIdx.x * 256 + threadIdx.x;
  if (e < E) atomicAdd(&deg[dst[e]], 1);
}

// ---------- K3: single-block exclusive scan (rowptr + cursor copy) ----------
__global__ void k_scan(const int* __restrict__ deg, int* __restrict__ rowptr,
                       int* __restrict__ cursor, int n) {
  __shared__ int wsum[16];
  __shared__ int ctot;
  const int tid = threadIdx.x;
  const int lane = tid & 63, wv = tid >> 6;
  int carry = 0;
  for (int base = 0; base < n; base += 1024) {
    int i = base + tid;
    int v = (i < n) ? deg[i] : 0;
    int s = v;
    #pragma unroll
    for (int d = 1; d < 64; d <<= 1) {      // inclusive wave scan
      int t = __shfl_up(s, d);
      if (lane >= d) s += t;
    }
    if (lane == 63) wsum[wv] = s;
    __syncthreads();
    if (tid == 0) {
      int run = 0;
      #pragma unroll
      for (int w = 0; w < 16; ++w) { int x = wsum[w]; wsum[w] = run; run += x; }
      ctot = run;
    }
    __syncthreads();
    if (i < n) {
      int excl = carry + wsum[wv] + (s - v);
      rowptr[i] = excl;
      cursor[i] = excl;
    }
    carry += ctot;
    __syncthreads();                        // protect wsum/ctot for next iter
  }
  if (tid == 0) rowptr[n] = carry;
}

// ---------- K4: scatter edges into dst-sorted src list ----------
__global__ void k_scatter(const int* __restrict__ src, const int* __restrict__ dst,
                          int* __restrict__ cursor, int* __restrict__ srcs, int E) {
  int e = blockIdx.x * 256 + threadIdx.x;
  if (e < E) {
    int pos = atomicAdd(&cursor[dst[e]], 1);
    srcs[pos] = src[e];
  }
}

// ---------- K5: weights -> bf16 col-major B [512 cols][256 k]; row j = concat(Wl[g,o,:], Wr[g,o,:]) ----------
__global__ void k_wconv(const float* __restrict__ Wlx, const float* __restrict__ Wrx,
                        const float* __restrict__ Wlh, const float* __restrict__ Wrh,
                        u16* __restrict__ Btx, u16* __restrict__ Bth) {
  int t = blockIdx.x * 256 + threadIdx.x;   // 0..32767
  int path = t >> 14;
  int rem = t & 16383;
  int j = rem >> 5;                          // output col (g*128+o)
  int k0 = (rem & 31) << 3;                  // k chunk of 8
  const float* Wl = path ? Wlh : Wlx;
  const float* Wr = path ? Wrh : Wrx;
  const float* s = (k0 < 128) ? (Wl + (size_t)j * 128 + k0) : (Wr + (size_t)j * 128 + (k0 - 128));
  u32 d0 = f2bf(s[0]) | (f2bf(s[1]) << 16);
  u32 d1 = f2bf(s[2]) | (f2bf(s[3]) << 16);
  u32 d2 = f2bf(s[4]) | (f2bf(s[5]) << 16);
  u32 d3 = f2bf(s[6]) | (f2bf(s[7]) << 16);
  u16* Bt = path ? Bth : Btx;
  *(uint4*)(Bt + (size_t)j * 256 + k0) = make_uint4(d0, d1, d2, d3);
}

// ---------- K6: wave-per-node mean aggregation (reads bf16 right halves, writes bf16 left halves) ----------
__global__ void k_agg(const int* __restrict__ rowptr, const int* __restrict__ srcs,
                      u32* __restrict__ Abx, u32* __restrict__ Abh, int n) {
  int node = (blockIdx.x * 256 + threadIdx.x) >> 6;
  int lane = threadIdx.x & 63;
  if (node >= n) return;
  int beg = rowptr[node], end = rowptr[node + 1];
  float ax0 = 0.f, ax1 = 0.f, ah0 = 0.f, ah1 = 0.f;
  for (int e = beg; e < end; ++e) {
    int s = srcs[e];
    u32 vx = Abx[((size_t)s << 7) + 64 + lane];
    u32 vh = Abh[((size_t)s << 7) + 64 + lane];
    ax0 += bflo(vx); ax1 += bfhi(vx);
    ah0 += bflo(vh); ah1 += bfhi(vh);
  }
  float inv = (end > beg) ? 1.0f / (float)(end - beg) : 0.0f;
  Abx[((size_t)node << 7) + lane] = f2bf(ax0 * inv) | (f2bf(ax1 * inv) << 16);
  Abh[((size_t)node << 7) + lane] = f2bf(ah0 * inv) | (f2bf(ah1 * inv) << 16);
}

// ---------- K7: fused GEMM (16 nodes/block, 8 waves = {x,h} x {4 gates}) + normalize + gates ----------
__global__ __launch_bounds__(512, 2) void k_gemm(
    const u16* __restrict__ Abx, const u16* __restrict__ Abh,
    const u16* __restrict__ Btx, const u16* __restrict__ Bth,
    const float* __restrict__ blx, const float* __restrict__ blh,
    const float* __restrict__ wc, const float* __restrict__ bg,
    const float* __restrict__ Cin, float* __restrict__ H2, float* __restrict__ C2) {
  __shared__ u16 As[2][16][256];        // 16 KB, XOR-swizzled (uint4 col ^ (row&7))
  __shared__ float s_s[4][16][128];     // 32 KB, col ^ (l4<<3) swizzle

  const int tid = threadIdx.x;
  const int node0 = blockIdx.x << 4;

  { // stage both A tiles: 1024 uint4
    uint4* As4 = (uint4*)As;
    const uint4* Gx = (const uint4*)Abx;
    const uint4* Gh = (const uint4*)Abh;
    #pragma unroll
    for (int it = 0; it < 2; ++it) {
      int i = it * 512 + tid;
      int p = i >> 9, rem = i & 511;
      int row = rem >> 5, c = rem & 31;              // 32 uint4 per 256-bf16 row
      const uint4* G = p ? Gh : Gx;
      As4[(p << 9) + (row << 5) + (c ^ (row & 7))] = G[((size_t)(node0 + row) << 5) + c];
    }
  }
  __syncthreads();

  const int wid = tid >> 6, lane = tid & 63;
  const int p = wid >> 2, g = wid & 3;               // path (0=x,1=h), gate
  const int l15 = lane & 15, l4 = lane >> 4;
  const u16* Bt = p ? Bth : Btx;
  const short8_t* As8 = (const short8_t*)As;

  f32x4_t acc[8];
  #pragma unroll
  for (int cf = 0; cf < 8; ++cf) acc[cf] = (f32x4_t){0.f, 0.f, 0.f, 0.f};

  #pragma unroll
  for (int ks = 0; ks < 8; ++ks) {
    // A frag: lane -> row=l15, k = ks*32 + l4*8 .. +7 (swizzled uint4 col)
    short8_t a = As8[(p << 9) + (l15 << 5) + ((ks * 4 + l4) ^ (l15 & 7))];
    #pragma unroll
    for (int cf = 0; cf < 8; ++cf) {
      // B frag: col = g*128 + cf*16 + l15, k = ks*32 + l4*8 (col-major rows, L2-resident)
      short8_t b = *(const short8_t*)(Bt + ((size_t)((g << 7) + (cf << 4) + l15) << 8) + (ks << 5) + (l4 << 3));
      acc[cf] = __builtin_amdgcn_mfma_f32_16x16x32_bf16(a, b, acc[cf], 0, 0, 0);
    }
  }

  // bias + sum of squares per output row (D layout: row=(l4*4+j), col=cf*16+l15)
  const float* bl = p ? blh : blx;
  float psum[4] = {0.f, 0.f, 0.f, 0.f};
  #pragma unroll
  for (int cf = 0; cf < 8; ++cf) {
    float bv = bl[(g << 7) + (cf << 4) + l15];
    #pragma unroll
    for (int j = 0; j < 4; ++j) {
      float v = acc[cf][j] + bv;
      acc[cf][j] = v;
      psum[j] += v * v;
    }
  }
  float rsc[4];
  #pragma unroll
  for (int j = 0; j < 4; ++j) {
    float s = psum[j];
    #pragma unroll
    for (int d = 1; d < 16; d <<= 1) s += __shfl_xor(s, d);   // reduce over 16-lane col group
    rsc[j] = 1.0f / fmaxf(sqrtf(s), 1e-12f);
  }

  // two-phase combine s = norm(x) + norm(h) in LDS
  if (p) {
    #pragma unroll
    for (int cf = 0; cf < 8; ++cf) {
      int c2 = ((cf << 4) + l15) ^ (l4 << 3);
      #pragma unroll
      for (int j = 0; j < 4; ++j) s_s[g][l4 * 4 + j][c2] = acc[cf][j] * rsc[j];
    }
  }
  __syncthreads();
  if (!p) {
    #pragma unroll
    for (int cf = 0; cf < 8; ++cf) {
      int c2 = ((cf << 4) + l15) ^ (l4 << 3);
      #pragma unroll
      for (int j = 0; j < 4; ++j) s_s[g][l4 * 4 + j][c2] += acc[cf][j] * rsc[j];
    }
  }
  __syncthreads();

  // gate math + store H2, C2
  #pragma unroll
  for (int k = 0; k < 4; ++k) {
    int idx = (k << 9) + tid;                 // 0..2047 = 16 nodes x 128
    int nn = idx >> 7, o = idx & 127;
    int os = o ^ ((nn >> 2) << 3);            // inverse of writer swizzle (l4 = nn>>2)
    float s0 = s_s[0][nn][os], s1 = s_s[1][nn][os], s2 = s_s[2][nn][os], s3 = s_s[3][nn][os];
    size_t gi = ((size_t)(node0 + nn) << 7) + o;
    float cv = Cin[gi];
    float vi = 1.0f / (1.0f + expf(-(s0 + wc[o] * cv + bg[o])));
    float vf = 1.0f / (1.0f + expf(-(s1 + wc[128 + o] * cv + bg[128 + o])));
    float vt = tanhf(s2 + bg[256 + o]);
    float c2v = vf * cv + vi * vt;
    float vo = 1.0f / (1.0f + expf(-(s3 + wc[256 + o] * c2v + bg[384 + o])));
    H2[gi] = vo * tanhf(c2v);
    C2[gi] = c2v;
  }
}

extern "C" void kernel_launch(void* const* d_in, const int* in_sizes, int n_in,
                              void* d_out, int out_size, void* d_ws, size_t ws_size,
                              hipStream_t stream) {
  const float* X = (const float*)d_in[0];
  const float* H = (const float*)d_in[1];
  const float* C = (const float*)d_in[2];
  const int* edges = (const int*)d_in[3];     // [2][E]: row0 = src, row1 = dst
  const float* Wlx = (const float*)d_in[4];
  const float* blx = (const float*)d_in[5];
  const float* Wrx = (const float*)d_in[6];
  const float* Wlh = (const float*)d_in[7];
  const float* blh = (const float*)d_in[8];
  const float* Wrh = (const float*)d_in[9];
  const float* wc  = (const float*)d_in[10];
  const float* bg  = (const float*)d_in[11];
  const int N = in_sizes[0] / 128;
  const int E = in_sizes[3] / 2;

  char* ws = (char*)d_ws;
  size_t off = 0;
  auto alloc = [&](size_t bytes) -> void* {
    void* pp = ws + off;
    off = (off + bytes + 511) & ~(size_t)511;
    return pp;
  };
  u32* Abx   = (u32*)alloc((size_t)N * 512);        // [N][256] bf16
  u32* Abh   = (u32*)alloc((size_t)N * 512);
  u16* Btx   = (u16*)alloc(512 * 512);              // [512][256] bf16
  u16* Bth   = (u16*)alloc(512 * 512);
  int* deg    = (int*)alloc((size_t)N * 4);
  int* rowptr = (int*)alloc(((size_t)N + 1) * 4);
  int* cursor = (int*)alloc((size_t)N * 4);
  int* srcs   = (int*)alloc((size_t)E * 4);

  hipMemsetAsync(deg, 0, (size_t)N * 4, stream);
  k_conv_xh<<<DIV_UP(N * 32, 256), 256, 0, stream>>>((const float4*)X, (const float4*)H, Abx, Abh, N * 32);
  k_hist<<<DIV_UP(E, 256), 256, 0, stream>>>(edges + E, deg, E);
  k_scan<<<1, 1024, 0, stream>>>(deg, rowptr, cursor, N);
  k_scatter<<<DIV_UP(E, 256), 256, 0, stream>>>(edges, edges + E, cursor, srcs, E);
  k_wconv<<<128, 256, 0, stream>>>(Wlx, Wrx, Wlh, Wrh, Btx, Bth);
  k_agg<<<DIV_UP(N * 64, 256), 256, 0, stream>>>(rowptr, srcs, Abx, Abh, N);

  float* H2 = (float*)d_out;
  float* C2 = H2 + (size_t)N * 128;
  k_gemm<<<N / 16, 512, 0, stream>>>((const u16*)Abx, (const u16*)Abh, Btx, Bth,
                                     blx, blh, wc, bg, C, H2, C2);
}

// Round 3
// 604.038 us; speedup vs baseline: 1.4176x; 1.4176x over previous
//
#include <hip/hip_runtime.h>
#include <hip/hip_bf16.h>
#include <hip/hip_fp16.h>

typedef __attribute__((ext_vector_type(8))) short short8_t;
typedef __attribute__((ext_vector_type(4))) float f32x4_t;
typedef unsigned short u16;
typedef unsigned int u32;

#define DIV_UP(a, b) (((a) + (b) - 1) / (b))

static __device__ __forceinline__ float bflo(u32 u) { return __uint_as_float(u << 16); }
static __device__ __forceinline__ float bfhi(u32 u) { return __uint_as_float(u & 0xffff0000u); }
static __device__ __forceinline__ u32 f2bf(float f) {
  u32 u = __float_as_uint(f);
  return (u + 0x7fffu + ((u >> 16) & 1u)) >> 16;  // RTNE
}

// ---------- K1: X,H f32 -> bf16 into right halves (cols 128..255) of A matrices ----------
__global__ void k_conv_xh(const float4* __restrict__ X, const float4* __restrict__ H,
                          u32* __restrict__ Abx, u32* __restrict__ Abh, int total) {
  int t = blockIdx.x * 256 + threadIdx.x;
  if (t >= total) return;                 // total = N*32 (float4 granules)
  int nrow = t >> 5, c = t & 31;
  float4 x = X[t], h = H[t];
  uint2 px = make_uint2(f2bf(x.x) | (f2bf(x.y) << 16), f2bf(x.z) | (f2bf(x.w) << 16));
  uint2 ph = make_uint2(f2bf(h.x) | (f2bf(h.y) << 16), f2bf(h.z) | (f2bf(h.w) << 16));
  ((uint2*)(Abx + (size_t)nrow * 128 + 64))[c] = px;   // A row = 256 bf16 = 128 dwords
  ((uint2*)(Abh + (size_t)nrow * 128 + 64))[c] = ph;
}

// ---------- K2: degree histogram ----------
__global__ void k_hist(const int* __restrict__ dst, int* __restrict__ deg, int E) {
  int e = blockIdx.x * 256 + threadIdx.x;
  if (e < E) atomicAdd(&deg[dst[e]], 1);
}

// ---------- K3: single-block exclusive scan, 4 elems/thread ----------
__global__ void k_scan(const int* __restrict__ deg, int* __restrict__ rowptr,
                       int* __restrict__ cursor, int n) {
  __shared__ int wsum[16];
  __shared__ int ctot;
  const int tid = threadIdx.x;
  const int lane = tid & 63, wv = tid >> 6;
  int carry = 0;
  for (int base = 0; base < n; base += 4096) {
    int i0 = base + tid * 4;
    int d0 = 0, d1 = 0, d2 = 0, d3 = 0;
    if (i0 + 3 < n) {
      int4 dd = *(const int4*)(deg + i0);
      d0 = dd.x; d1 = dd.y; d2 = dd.z; d3 = dd.w;
    } else {
      if (i0 < n) d0 = deg[i0];
      if (i0 + 1 < n) d1 = deg[i0 + 1];
      if (i0 + 2 < n) d2 = deg[i0 + 2];
      if (i0 + 3 < n) d3 = deg[i0 + 3];
    }
    int v = d0 + d1 + d2 + d3;
    int s = v;
    #pragma unroll
    for (int d = 1; d < 64; d <<= 1) {      // inclusive wave scan of thread sums
      int t = __shfl_up(s, d);
      if (lane >= d) s += t;
    }
    if (lane == 63) wsum[wv] = s;
    __syncthreads();
    if (tid == 0) {
      int run = 0;
      #pragma unroll
      for (int w = 0; w < 16; ++w) { int x = wsum[w]; wsum[w] = run; run += x; }
      ctot = run;
    }
    __syncthreads();
    if (i0 < n) {
      int p0 = carry + wsum[wv] + (s - v);
      rowptr[i0] = p0; cursor[i0] = p0;
      int p1 = p0 + d0;
      if (i0 + 1 < n) { rowptr[i0 + 1] = p1; cursor[i0 + 1] = p1; }
      int p2 = p1 + d1;
      if (i0 + 2 < n) { rowptr[i0 + 2] = p2; cursor[i0 + 2] = p2; }
      int p3 = p2 + d2;
      if (i0 + 3 < n) { rowptr[i0 + 3] = p3; cursor[i0 + 3] = p3; }
    }
    carry += ctot;
    __syncthreads();                        // protect wsum/ctot for next iter
  }
  if (tid == 0) rowptr[n] = carry;
}

// ---------- K4: scatter edges into dst-sorted src list ----------
__global__ void k_scatter(const int* __restrict__ src, const int* __restrict__ dst,
                          int* __restrict__ cursor, int* __restrict__ srcs, int E) {
  int e = blockIdx.x * 256 + threadIdx.x;
  if (e < E) {
    int pos = atomicAdd(&cursor[dst[e]], 1);
    srcs[pos] = src[e];
  }
}

// ---------- K5: weights -> bf16 B in MFMA-fragment order ----------
// B element (col j, k) -> Bt[(((colgrp*8 + ks)*4 + l4)*16 + c16)*8 + k8]
//   colgrp=j>>4, c16=j&15, ks=k>>5, l4=(k&31)>>3, k8=k&7
// so a wave's (colgrp, ks) fragment = contiguous 1 KB, lane*16B.
__global__ void k_wconv(const float* __restrict__ Wlx, const float* __restrict__ Wrx,
                        const float* __restrict__ Wlh, const float* __restrict__ Wrh,
                        u16* __restrict__ Btx, u16* __restrict__ Bth) {
  int t = blockIdx.x * 256 + threadIdx.x;   // 0..32767
  int path = t >> 14;
  int rem = t & 16383;
  int j = rem >> 5;                          // output col (g*128+o), 0..511
  int kc = rem & 31;                         // k chunk of 8
  int k0 = kc << 3;
  const float* Wl = path ? Wlh : Wlx;
  const float* Wr = path ? Wrh : Wrx;
  const float* s = (k0 < 128) ? (Wl + (size_t)j * 128 + k0) : (Wr + (size_t)j * 128 + (k0 - 128));
  u32 d0 = f2bf(s[0]) | (f2bf(s[1]) << 16);
  u32 d1 = f2bf(s[2]) | (f2bf(s[3]) << 16);
  u32 d2 = f2bf(s[4]) | (f2bf(s[5]) << 16);
  u32 d3 = f2bf(s[6]) | (f2bf(s[7]) << 16);
  u16* Bt = path ? Bth : Btx;
  int colgrp = j >> 4, c16 = j & 15;
  int ks = kc >> 2, l4 = kc & 3;
  *(uint4*)(Bt + ((((((colgrp << 3) + ks) << 2) + l4) << 4) + c16) * 8) = make_uint4(d0, d1, d2, d3);
}

// ---------- K6: wave-per-node mean aggregation (unrolled x4 for MLP) ----------
__global__ void k_agg(const int* __restrict__ rowptr, const int* __restrict__ srcs,
                      u32* __restrict__ Abx, u32* __restrict__ Abh, int n) {
  int node = (blockIdx.x * 256 + threadIdx.x) >> 6;
  int lane = threadIdx.x & 63;
  if (node >= n) return;
  int beg = rowptr[node], end = rowptr[node + 1];
  float ax0 = 0.f, ax1 = 0.f, ah0 = 0.f, ah1 = 0.f;
  int e = beg;
  for (; e + 4 <= end; e += 4) {
    int s0 = srcs[e], s1 = srcs[e + 1], s2 = srcs[e + 2], s3 = srcs[e + 3];
    u32 vx0 = Abx[((size_t)s0 << 7) + 64 + lane];
    u32 vx1 = Abx[((size_t)s1 << 7) + 64 + lane];
    u32 vx2 = Abx[((size_t)s2 << 7) + 64 + lane];
    u32 vx3 = Abx[((size_t)s3 << 7) + 64 + lane];
    u32 vh0 = Abh[((size_t)s0 << 7) + 64 + lane];
    u32 vh1 = Abh[((size_t)s1 << 7) + 64 + lane];
    u32 vh2 = Abh[((size_t)s2 << 7) + 64 + lane];
    u32 vh3 = Abh[((size_t)s3 << 7) + 64 + lane];
    ax0 += bflo(vx0) + bflo(vx1) + bflo(vx2) + bflo(vx3);
    ax1 += bfhi(vx0) + bfhi(vx1) + bfhi(vx2) + bfhi(vx3);
    ah0 += bflo(vh0) + bflo(vh1) + bflo(vh2) + bflo(vh3);
    ah1 += bfhi(vh0) + bfhi(vh1) + bfhi(vh2) + bfhi(vh3);
  }
  for (; e < end; ++e) {
    int s = srcs[e];
    u32 vx = Abx[((size_t)s << 7) + 64 + lane];
    u32 vh = Abh[((size_t)s << 7) + 64 + lane];
    ax0 += bflo(vx); ax1 += bfhi(vx);
    ah0 += bflo(vh); ah1 += bfhi(vh);
  }
  float inv = (end > beg) ? 1.0f / (float)(end - beg) : 0.0f;
  Abx[((size_t)node << 7) + lane] = f2bf(ax0 * inv) | (f2bf(ax1 * inv) << 16);
  Abh[((size_t)node << 7) + lane] = f2bf(ah0 * inv) | (f2bf(ah1 * inv) << 16);
}

// ---------- K7: fused GEMM (64 nodes/block, 8 waves = {x,h} x {4 gates}) ----------
// Each wave: 64 rows x 128 cols, K=256. A from swizzled LDS, B from global
// (fragment-ordered, 1KB contiguous per load). LDS reused for f16 s-combine.
__global__ __launch_bounds__(512, 2) void k_gemm(
    const u16* __restrict__ Abx, const u16* __restrict__ Abh,
    const u16* __restrict__ Btx, const u16* __restrict__ Bth,
    const float* __restrict__ blx, const float* __restrict__ blh,
    const float* __restrict__ wc, const float* __restrict__ bg,
    const float* __restrict__ Cin, float* __restrict__ H2, float* __restrict__ C2,
    int N) {
  __shared__ char smem[65536];          // union: As [2][64][256]bf16 | sbuf [4][64][128]f16
  uint4* As4 = (uint4*)smem;
  __half* sbuf = (__half*)smem;

  const int tid = threadIdx.x;
  const int node0 = blockIdx.x << 6;

  { // stage both A tiles: 4096 uint4, XOR-swizzled (uint4 col ^ (row&7))
    const uint4* Gx = (const uint4*)Abx;
    const uint4* Gh = (const uint4*)Abh;
    #pragma unroll
    for (int it = 0; it < 8; ++it) {
      int i = it * 512 + tid;
      int p = i >> 11, rem = i & 2047;
      int row = rem >> 5, c = rem & 31;              // 32 uint4 per 256-bf16 row
      int gr = node0 + row; if (gr >= N) gr = N - 1; // clamp tail (dup last row)
      const uint4* G = p ? Gh : Gx;
      As4[(((p << 6) + row) << 5) + (c ^ (row & 7))] = G[(size_t)gr << 5 | c];
    }
  }
  __syncthreads();

  const int wid = tid >> 6, lane = tid & 63;
  const int p = wid >> 2, g = wid & 3;               // path (0=x,1=h), gate
  const int l15 = lane & 15, l4 = lane >> 4;
  const u16* Bt = p ? Bth : Btx;
  const short8_t* As8 = (const short8_t*)smem;

  f32x4_t acc[4][8];
  #pragma unroll
  for (int rf = 0; rf < 4; ++rf)
    #pragma unroll
    for (int cf = 0; cf < 8; ++cf) acc[rf][cf] = (f32x4_t){0.f, 0.f, 0.f, 0.f};

  #pragma unroll
  for (int ks = 0; ks < 8; ++ks) {
    short8_t b[8];
    #pragma unroll
    for (int cf = 0; cf < 8; ++cf)
      b[cf] = *(const short8_t*)(Bt + (size_t)((((g << 3) + cf) << 3) + ks) * 512 + lane * 8);
    short8_t a[4];
    #pragma unroll
    for (int rf = 0; rf < 4; ++rf)
      a[rf] = As8[(((p << 6) + (rf << 4) + l15) << 5) + (((ks << 2) + l4) ^ (l15 & 7))];
    #pragma unroll
    for (int rf = 0; rf < 4; ++rf)
      #pragma unroll
      for (int cf = 0; cf < 8; ++cf)
        acc[rf][cf] = __builtin_amdgcn_mfma_f32_16x16x32_bf16(a[rf], b[cf], acc[rf][cf], 0, 0, 0);
  }

  // bias + L2-norm per output row (D layout: row = rf*16 + l4*4 + j, col = cf*16 + l15)
  const float* bl = p ? blh : blx;
  float bv[8];
  #pragma unroll
  for (int cf = 0; cf < 8; ++cf) bv[cf] = bl[(g << 7) + (cf << 4) + l15];
  float rsc[4][4];
  #pragma unroll
  for (int rf = 0; rf < 4; ++rf) {
    float ps[4] = {0.f, 0.f, 0.f, 0.f};
    #pragma unroll
    for (int cf = 0; cf < 8; ++cf)
      #pragma unroll
      for (int j = 0; j < 4; ++j) {
        float v = acc[rf][cf][j] + bv[cf];
        acc[rf][cf][j] = v;
        ps[j] += v * v;
      }
    #pragma unroll
    for (int j = 0; j < 4; ++j) {
      float s = ps[j];
      #pragma unroll
      for (int d = 1; d < 16; d <<= 1) s += __shfl_xor(s, d);   // 16-lane col group
      rsc[rf][j] = 1.0f / fmaxf(sqrtf(s), 1e-12f);
    }
  }

  __syncthreads();   // everyone done reading As; reuse LDS as sbuf
  if (p == 0) {
    #pragma unroll
    for (int rf = 0; rf < 4; ++rf)
      #pragma unroll
      for (int cf = 0; cf < 8; ++cf)
        #pragma unroll
        for (int j = 0; j < 4; ++j)
          sbuf[(g << 13) + (((rf << 4) + (l4 << 2) + j) << 7) + (cf << 4) + l15] =
              __float2half(acc[rf][cf][j] * rsc[rf][j]);
  }
  __syncthreads();
  if (p == 1) {
    #pragma unroll
    for (int rf = 0; rf < 4; ++rf)
      #pragma unroll
      for (int cf = 0; cf < 8; ++cf)
        #pragma unroll
        for (int j = 0; j < 4; ++j) {
          int ix = (g << 13) + (((rf << 4) + (l4 << 2) + j) << 7) + (cf << 4) + l15;
          sbuf[ix] = __float2half(__half2float(sbuf[ix]) + acc[rf][cf][j] * rsc[rf][j]);
        }
  }
  __syncthreads();

  // gate math + store H2, C2 (64 nodes x 128 = 8192 elems, 16 per thread)
  #pragma unroll
  for (int k = 0; k < 16; ++k) {
    int idx = (k << 9) + tid;
    int nn = idx >> 7, o = idx & 127;
    if (node0 + nn >= N) continue;
    float s0 = __half2float(sbuf[(nn << 7) + o]);
    float s1 = __half2float(sbuf[8192 + (nn << 7) + o]);
    float s2 = __half2float(sbuf[16384 + (nn << 7) + o]);
    float s3 = __half2float(sbuf[24576 + (nn << 7) + o]);
    size_t gi = ((size_t)(node0 + nn) << 7) + o;
    float cv = Cin[gi];
    float vi = 1.0f / (1.0f + expf(-(s0 + wc[o] * cv + bg[o])));
    float vf = 1.0f / (1.0f + expf(-(s1 + wc[128 + o] * cv + bg[128 + o])));
    float vt = tanhf(s2 + bg[256 + o]);
    float c2v = vf * cv + vi * vt;
    float vo = 1.0f / (1.0f + expf(-(s3 + wc[256 + o] * c2v + bg[384 + o])));
    H2[gi] = vo * tanhf(c2v);
    C2[gi] = c2v;
  }
}

extern "C" void kernel_launch(void* const* d_in, const int* in_sizes, int n_in,
                              void* d_out, int out_size, void* d_ws, size_t ws_size,
                              hipStream_t stream) {
  const float* X = (const float*)d_in[0];
  const float* H = (const float*)d_in[1];
  const float* C = (const float*)d_in[2];
  const int* edges = (const int*)d_in[3];     // [2][E]: row0 = src, row1 = dst
  const float* Wlx = (const float*)d_in[4];
  const float* blx = (const float*)d_in[5];
  const float* Wrx = (const float*)d_in[6];
  const float* Wlh = (const float*)d_in[7];
  const float* blh = (const float*)d_in[8];
  const float* Wrh = (const float*)d_in[9];
  const float* wc  = (const float*)d_in[10];
  const float* bg  = (const float*)d_in[11];
  const int N = in_sizes[0] / 128;
  const int E = in_sizes[3] / 2;

  char* ws = (char*)d_ws;
  size_t off = 0;
  auto alloc = [&](size_t bytes) -> void* {
    void* pp = ws + off;
    off = (off + bytes + 511) & ~(size_t)511;
    return pp;
  };
  u32* Abx   = (u32*)alloc((size_t)N * 512);        // [N][256] bf16
  u32* Abh   = (u32*)alloc((size_t)N * 512);
  u16* Btx   = (u16*)alloc(512 * 512);              // fragment-ordered bf16 B
  u16* Bth   = (u16*)alloc(512 * 512);
  int* deg    = (int*)alloc((size_t)N * 4);
  int* rowptr = (int*)alloc(((size_t)N + 1) * 4);
  int* cursor = (int*)alloc((size_t)N * 4);
  int* srcs   = (int*)alloc((size_t)E * 4);

  hipMemsetAsync(deg, 0, (size_t)N * 4, stream);
  k_conv_xh<<<DIV_UP(N * 32, 256), 256, 0, stream>>>((const float4*)X, (const float4*)H, Abx, Abh, N * 32);
  k_hist<<<DIV_UP(E, 256), 256, 0, stream>>>(edges + E, deg, E);
  k_scan<<<1, 1024, 0, stream>>>(deg, rowptr, cursor, N);
  k_scatter<<<DIV_UP(E, 256), 256, 0, stream>>>(edges, edges + E, cursor, srcs, E);
  k_wconv<<<128, 256, 0, stream>>>(Wlx, Wrx, Wlh, Wrh, Btx, Bth);
  k_agg<<<DIV_UP(N * 64, 256), 256, 0, stream>>>(rowptr, srcs, Abx, Abh, N);

  float* H2 = (float*)d_out;
  float* C2 = H2 + (size_t)N * 128;
  k_gemm<<<DIV_UP(N, 64), 512, 0, stream>>>((const u16*)Abx, (const u16*)Abh, Btx, Bth,
                                            blx, blh, wc, bg, C, H2, C2, N);
}

// Round 4
// 549.167 us; speedup vs baseline: 1.5592x; 1.0999x over previous
//
#include <hip/hip_runtime.h>
#include <hip/hip_bf16.h>
#include <hip/hip_fp16.h>

typedef __attribute__((ext_vector_type(8))) short short8_t;
typedef __attribute__((ext_vector_type(4))) float f32x4_t;
typedef unsigned short u16;
typedef unsigned int u32;

#define DIV_UP(a, b) (((a) + (b) - 1) / (b))

static __device__ __forceinline__ float bflo(u32 u) { return __uint_as_float(u << 16); }
static __device__ __forceinline__ float bfhi(u32 u) { return __uint_as_float(u & 0xffff0000u); }
static __device__ __forceinline__ u32 f2bf(float f) {
  u32 u = __float_as_uint(f);
  return (u + 0x7fffu + ((u >> 16) & 1u)) >> 16;  // RTNE
}
static __device__ __forceinline__ float fsig(float x) {
  return __builtin_amdgcn_rcpf(1.0f + __expf(-x));
}
static __device__ __forceinline__ float ftanh(float x) {
  float cx = fminf(fmaxf(x, -15.0f), 15.0f);
  float t = __expf(2.0f * cx);
  return (t - 1.0f) * __builtin_amdgcn_rcpf(t + 1.0f);
}
static __device__ __forceinline__ float h2f_bits(u32 dw, int hi) {
  return __half2float(__ushort_as_half((u16)(hi ? (dw >> 16) : (dw & 0xffffu))));
}

// ---------- K1: X,H f32 -> bf16 into right halves (cols 128..255) of A matrices ----------
__global__ void k_conv_xh(const float4* __restrict__ X, const float4* __restrict__ H,
                          u32* __restrict__ Abx, u32* __restrict__ Abh, int total) {
  int t = blockIdx.x * 256 + threadIdx.x;
  if (t >= total) return;                 // total = N*32 (float4 granules)
  int nrow = t >> 5, c = t & 31;
  float4 x = X[t], h = H[t];
  uint2 px = make_uint2(f2bf(x.x) | (f2bf(x.y) << 16), f2bf(x.z) | (f2bf(x.w) << 16));
  uint2 ph = make_uint2(f2bf(h.x) | (f2bf(h.y) << 16), f2bf(h.z) | (f2bf(h.w) << 16));
  ((uint2*)(Abx + (size_t)nrow * 128 + 64))[c] = px;   // A row = 256 bf16 = 128 dwords
  ((uint2*)(Abh + (size_t)nrow * 128 + 64))[c] = ph;
}

// ---------- K2: degree histogram ----------
__global__ void k_hist(const int* __restrict__ dst, int* __restrict__ deg, int E) {
  int e = blockIdx.x * 256 + threadIdx.x;
  if (e < E) atomicAdd(&deg[dst[e]], 1);
}

// ---------- K3: single-block exclusive scan, 4 elems/thread ----------
__global__ void k_scan(const int* __restrict__ deg, int* __restrict__ rowptr,
                       int* __restrict__ cursor, int n) {
  __shared__ int wsum[16];
  __shared__ int ctot;
  const int tid = threadIdx.x;
  const int lane = tid & 63, wv = tid >> 6;
  int carry = 0;
  for (int base = 0; base < n; base += 4096) {
    int i0 = base + tid * 4;
    int d0 = 0, d1 = 0, d2 = 0, d3 = 0;
    if (i0 + 3 < n) {
      int4 dd = *(const int4*)(deg + i0);
      d0 = dd.x; d1 = dd.y; d2 = dd.z; d3 = dd.w;
    } else {
      if (i0 < n) d0 = deg[i0];
      if (i0 + 1 < n) d1 = deg[i0 + 1];
      if (i0 + 2 < n) d2 = deg[i0 + 2];
      if (i0 + 3 < n) d3 = deg[i0 + 3];
    }
    int v = d0 + d1 + d2 + d3;
    int s = v;
    #pragma unroll
    for (int d = 1; d < 64; d <<= 1) {      // inclusive wave scan of thread sums
      int t = __shfl_up(s, d);
      if (lane >= d) s += t;
    }
    if (lane == 63) wsum[wv] = s;
    __syncthreads();
    if (tid == 0) {
      int run = 0;
      #pragma unroll
      for (int w = 0; w < 16; ++w) { int x = wsum[w]; wsum[w] = run; run += x; }
      ctot = run;
    }
    __syncthreads();
    if (i0 < n) {
      int p0 = carry + wsum[wv] + (s - v);
      rowptr[i0] = p0; cursor[i0] = p0;
      int p1 = p0 + d0;
      if (i0 + 1 < n) { rowptr[i0 + 1] = p1; cursor[i0 + 1] = p1; }
      int p2 = p1 + d1;
      if (i0 + 2 < n) { rowptr[i0 + 2] = p2; cursor[i0 + 2] = p2; }
      int p3 = p2 + d2;
      if (i0 + 3 < n) { rowptr[i0 + 3] = p3; cursor[i0 + 3] = p3; }
    }
    carry += ctot;
    __syncthreads();                        // protect wsum/ctot for next iter
  }
  if (tid == 0) rowptr[n] = carry;
}

// ---------- K4: scatter edges into dst-sorted src list ----------
__global__ void k_scatter(const int* __restrict__ src, const int* __restrict__ dst,
                          int* __restrict__ cursor, int* __restrict__ srcs, int E) {
  int e = blockIdx.x * 256 + threadIdx.x;
  if (e < E) {
    int pos = atomicAdd(&cursor[dst[e]], 1);
    srcs[pos] = src[e];
  }
}

// ---------- K5: weights -> bf16 B in MFMA-fragment order ----------
// B element (col j, k) -> Bt[(((colgrp*8 + ks)*4 + l4)*16 + c16)*8 + k8]
__global__ void k_wconv(const float* __restrict__ Wlx, const float* __restrict__ Wrx,
                        const float* __restrict__ Wlh, const float* __restrict__ Wrh,
                        u16* __restrict__ Btx, u16* __restrict__ Bth) {
  int t = blockIdx.x * 256 + threadIdx.x;   // 0..32767
  int path = t >> 14;
  int rem = t & 16383;
  int j = rem >> 5;                          // output col (g*128+o), 0..511
  int kc = rem & 31;                         // k chunk of 8
  int k0 = kc << 3;
  const float* Wl = path ? Wlh : Wlx;
  const float* Wr = path ? Wrh : Wrx;
  const float* s = (k0 < 128) ? (Wl + (size_t)j * 128 + k0) : (Wr + (size_t)j * 128 + (k0 - 128));
  u32 d0 = f2bf(s[0]) | (f2bf(s[1]) << 16);
  u32 d1 = f2bf(s[2]) | (f2bf(s[3]) << 16);
  u32 d2 = f2bf(s[4]) | (f2bf(s[5]) << 16);
  u32 d3 = f2bf(s[6]) | (f2bf(s[7]) << 16);
  u16* Bt = path ? Bth : Btx;
  int colgrp = j >> 4, c16 = j & 15;
  int ks = kc >> 2, l4 = kc & 3;
  *(uint4*)(Bt + ((((((colgrp << 3) + ks) << 2) + l4) << 4) + c16) * 8) = make_uint4(d0, d1, d2, d3);
}

// ---------- K6: wave-per-node mean aggregation ----------
// lane quads: q0 = Abx edge a, q1 = Abh edge a, q2 = Abx edge b, q3 = Abh edge b.
// Each lane loads uint4 (16 B); 16 lanes cover a 256 B half-row. shfl_xor(32) combines pairs.
__global__ void k_agg(const int* __restrict__ rowptr, const int* __restrict__ srcs,
                      u32* __restrict__ Abx, u32* __restrict__ Abh, int n) {
  int node = (blockIdx.x * 256 + threadIdx.x) >> 6;
  int lane = threadIdx.x & 63;
  if (node >= n) return;
  int q = lane >> 4, l16 = lane & 15;
  int sel = q >> 1;                       // 0: edge a, 1: edge b
  const u32* M = (q & 1) ? Abh : Abx;
  int beg = rowptr[node], end = rowptr[node + 1];
  float a0 = 0, a1 = 0, a2 = 0, a3 = 0, a4 = 0, a5 = 0, a6 = 0, a7 = 0;
  int e = beg;
  for (; e + 4 <= end; e += 4) {
    int sA = srcs[e + sel];
    int sB = srcs[e + 2 + sel];
    uint4 vA = *((const uint4*)(M + ((size_t)sA << 7) + 64) + l16);
    uint4 vB = *((const uint4*)(M + ((size_t)sB << 7) + 64) + l16);
    a0 += bflo(vA.x) + bflo(vB.x); a1 += bfhi(vA.x) + bfhi(vB.x);
    a2 += bflo(vA.y) + bflo(vB.y); a3 += bfhi(vA.y) + bfhi(vB.y);
    a4 += bflo(vA.z) + bflo(vB.z); a5 += bfhi(vA.z) + bfhi(vB.z);
    a6 += bflo(vA.w) + bflo(vB.w); a7 += bfhi(vA.w) + bfhi(vB.w);
  }
  if (e + 2 <= end) {
    int sA = srcs[e + sel];
    uint4 v = *((const uint4*)(M + ((size_t)sA << 7) + 64) + l16);
    a0 += bflo(v.x); a1 += bfhi(v.x); a2 += bflo(v.y); a3 += bfhi(v.y);
    a4 += bflo(v.z); a5 += bfhi(v.z); a6 += bflo(v.w); a7 += bfhi(v.w);
    e += 2;
  }
  if (e < end && sel == 0) {              // single leftover edge: only edge-a quads
    int sA = srcs[e];
    uint4 v = *((const uint4*)(M + ((size_t)sA << 7) + 64) + l16);
    a0 += bflo(v.x); a1 += bfhi(v.x); a2 += bflo(v.y); a3 += bfhi(v.y);
    a4 += bflo(v.z); a5 += bfhi(v.z); a6 += bflo(v.w); a7 += bfhi(v.w);
  }
  a0 += __shfl_xor(a0, 32); a1 += __shfl_xor(a1, 32);
  a2 += __shfl_xor(a2, 32); a3 += __shfl_xor(a3, 32);
  a4 += __shfl_xor(a4, 32); a5 += __shfl_xor(a5, 32);
  a6 += __shfl_xor(a6, 32); a7 += __shfl_xor(a7, 32);
  int deg = end - beg;
  float inv = (deg > 0) ? (1.0f / (float)deg) : 0.0f;
  uint4 out = make_uint4(f2bf(a0 * inv) | (f2bf(a1 * inv) << 16),
                         f2bf(a2 * inv) | (f2bf(a3 * inv) << 16),
                         f2bf(a4 * inv) | (f2bf(a5 * inv) << 16),
                         f2bf(a6 * inv) | (f2bf(a7 * inv) << 16));
  if (q == 0)      ((uint4*)(Abx + ((size_t)node << 7)))[l16] = out;
  else if (q == 1) ((uint4*)(Abh + ((size_t)node << 7)))[l16] = out;
}

// ---------- K7: fused GEMM (64 nodes/block, 8 waves = {x,h} x {4 gates}) ----------
__global__ __launch_bounds__(512, 2) void k_gemm(
    const u16* __restrict__ Abx, const u16* __restrict__ Abh,
    const u16* __restrict__ Btx, const u16* __restrict__ Bth,
    const float* __restrict__ blx, const float* __restrict__ blh,
    const float* __restrict__ wc, const float* __restrict__ bg,
    const float* __restrict__ Cin, float* __restrict__ H2, float* __restrict__ C2,
    int N) {
  __shared__ char smem[65536];          // union: As [2][64][256]bf16 | sbuf [4][64][128]f16
  uint4* As4 = (uint4*)smem;
  __half* sbuf = (__half*)smem;

  const int tid = threadIdx.x;
  const int node0 = blockIdx.x << 6;

  { // stage both A tiles: 4096 uint4, XOR-swizzled (uint4 col ^ (row&7))
    const uint4* Gx = (const uint4*)Abx;
    const uint4* Gh = (const uint4*)Abh;
    #pragma unroll
    for (int it = 0; it < 8; ++it) {
      int i = it * 512 + tid;
      int p = i >> 11, rem = i & 2047;
      int row = rem >> 5, c = rem & 31;              // 32 uint4 per 256-bf16 row
      int gr = node0 + row; if (gr >= N) gr = N - 1; // clamp tail (dup last row)
      const uint4* G = p ? Gh : Gx;
      As4[(((p << 6) + row) << 5) + (c ^ (row & 7))] = G[((size_t)gr << 5) | c];
    }
  }
  __syncthreads();

  const int wid = tid >> 6, lane = tid & 63;
  const int p = wid >> 2, g = wid & 3;               // path (0=x,1=h), gate
  const int l15 = lane & 15, l4 = lane >> 4;
  const u16* Bt = p ? Bth : Btx;
  const short8_t* As8 = (const short8_t*)smem;

  f32x4_t acc[4][8];
  #pragma unroll
  for (int rf = 0; rf < 4; ++rf)
    #pragma unroll
    for (int cf = 0; cf < 8; ++cf) acc[rf][cf] = (f32x4_t){0.f, 0.f, 0.f, 0.f};

  #pragma unroll
  for (int ks = 0; ks < 8; ++ks) {
    short8_t b[8];
    #pragma unroll
    for (int cf = 0; cf < 8; ++cf)
      b[cf] = *(const short8_t*)(Bt + (size_t)((((g << 3) + cf) << 3) + ks) * 512 + lane * 8);
    short8_t a[4];
    #pragma unroll
    for (int rf = 0; rf < 4; ++rf)
      a[rf] = As8[(((p << 6) + (rf << 4) + l15) << 5) + (((ks << 2) + l4) ^ (l15 & 7))];
    #pragma unroll
    for (int rf = 0; rf < 4; ++rf)
      #pragma unroll
      for (int cf = 0; cf < 8; ++cf)
        acc[rf][cf] = __builtin_amdgcn_mfma_f32_16x16x32_bf16(a[rf], b[cf], acc[rf][cf], 0, 0, 0);
  }

  // bias + L2-norm per output row (D layout: row = rf*16 + l4*4 + j, col = cf*16 + l15)
  const float* bl = p ? blh : blx;
  float bv[8];
  #pragma unroll
  for (int cf = 0; cf < 8; ++cf) bv[cf] = bl[(g << 7) + (cf << 4) + l15];
  float rsc[4][4];
  #pragma unroll
  for (int rf = 0; rf < 4; ++rf) {
    float ps[4] = {0.f, 0.f, 0.f, 0.f};
    #pragma unroll
    for (int cf = 0; cf < 8; ++cf)
      #pragma unroll
      for (int j = 0; j < 4; ++j) {
        float v = acc[rf][cf][j] + bv[cf];
        acc[rf][cf][j] = v;
        ps[j] += v * v;
      }
    #pragma unroll
    for (int j = 0; j < 4; ++j) {
      float s = ps[j];
      #pragma unroll
      for (int d = 1; d < 16; d <<= 1) s += __shfl_xor(s, d);   // 16-lane col group
      rsc[rf][j] = __builtin_amdgcn_rsqf(fmaxf(s, 1e-24f));
    }
  }

  __syncthreads();   // everyone done reading As; reuse LDS as sbuf
  // sbuf layout: [g][row][col] f16 with col-granule swizzle cf' = cf ^ (row&7)
  if (p == 0) {
    #pragma unroll
    for (int rf = 0; rf < 4; ++rf)
      #pragma unroll
      for (int j = 0; j < 4; ++j) {
        int row = (rf << 4) + (l4 << 2) + j;
        #pragma unroll
        for (int cf = 0; cf < 8; ++cf)
          sbuf[(g << 13) + (row << 7) + (((cf ^ (row & 7)) << 4) + l15)] =
              __float2half(acc[rf][cf][j] * rsc[rf][j]);
      }
  }
  __syncthreads();
  if (p == 1) {
    #pragma unroll
    for (int rf = 0; rf < 4; ++rf)
      #pragma unroll
      for (int j = 0; j < 4; ++j) {
        int row = (rf << 4) + (l4 << 2) + j;
        #pragma unroll
        for (int cf = 0; cf < 8; ++cf) {
          int ix = (g << 13) + (row << 7) + (((cf ^ (row & 7)) << 4) + l15);
          sbuf[ix] = __float2half(__half2float(sbuf[ix]) + acc[rf][cf][j] * rsc[rf][j]);
        }
      }
  }
  __syncthreads();

  // epilogue: thread = (row nn, 16 cols at oc); vectorized loads + fast math
  {
    int nn = tid >> 3, oc = (tid & 7) << 4;
    if (node0 + nn < N) {
      int gi = (tid & 7) ^ (nn & 7);      // physical granule (undo swizzle)
      uint4 w[4][2];
      #pragma unroll
      for (int gg = 0; gg < 4; ++gg) {
        const uint4* ps = (const uint4*)(sbuf + (gg << 13) + (nn << 7) + (gi << 4));
        w[gg][0] = ps[0]; w[gg][1] = ps[1];
      }
      size_t gbase = (((size_t)(node0 + nn)) << 7) + oc;
      #pragma unroll
      for (int v = 0; v < 4; ++v) {       // 4 cols per chunk
        int o = oc + (v << 2);
        float4 cv  = *(const float4*)(Cin + gbase + (v << 2));
        float4 wci = *(const float4*)(wc + o);
        float4 wcf = *(const float4*)(wc + 128 + o);
        float4 wco = *(const float4*)(wc + 256 + o);
        float4 bgi = *(const float4*)(bg + o);
        float4 bgf = *(const float4*)(bg + 128 + o);
        float4 bgc = *(const float4*)(bg + 256 + o);
        float4 bgo = *(const float4*)(bg + 384 + o);
        float4 h2o, c2o;
        #pragma unroll
        for (int k = 0; k < 4; ++k) {
          int j = (v << 2) + k;           // 0..15
          int dw = j >> 2, hi2 = (j >> 1) & 1, hib = j & 1;
          u32 d0 = (dw == 0) ? (hi2 ? w[0][0].y : w[0][0].x) : (dw == 1) ? (hi2 ? w[0][0].w : w[0][0].z)
                 : (dw == 2) ? (hi2 ? w[0][1].y : w[0][1].x) : (hi2 ? w[0][1].w : w[0][1].z);
          u32 d1 = (dw == 0) ? (hi2 ? w[1][0].y : w[1][0].x) : (dw == 1) ? (hi2 ? w[1][0].w : w[1][0].z)
                 : (dw == 2) ? (hi2 ? w[1][1].y : w[1][1].x) : (hi2 ? w[1][1].w : w[1][1].z);
          u32 d2 = (dw == 0) ? (hi2 ? w[2][0].y : w[2][0].x) : (dw == 1) ? (hi2 ? w[2][0].w : w[2][0].z)
                 : (dw == 2) ? (hi2 ? w[2][1].y : w[2][1].x) : (hi2 ? w[2][1].w : w[2][1].z);
          u32 d3 = (dw == 0) ? (hi2 ? w[3][0].y : w[3][0].x) : (dw == 1) ? (hi2 ? w[3][0].w : w[3][0].z)
                 : (dw == 2) ? (hi2 ? w[3][1].y : w[3][1].x) : (hi2 ? w[3][1].w : w[3][1].z);
          float s0 = h2f_bits(d0, hib), s1 = h2f_bits(d1, hib);
          float s2 = h2f_bits(d2, hib), s3 = h2f_bits(d3, hib);
          float cvk = (&cv.x)[k];
          float vi = fsig(s0 + (&wci.x)[k] * cvk + (&bgi.x)[k]);
          float vf = fsig(s1 + (&wcf.x)[k] * cvk + (&bgf.x)[k]);
          float vt = ftanh(s2 + (&bgc.x)[k]);
          float c2v = vf * cvk + vi * vt;
          float vo = fsig(s3 + (&wco.x)[k] * c2v + (&bgo.x)[k]);
          (&h2o.x)[k] = vo * ftanh(c2v);
          (&c2o.x)[k] = c2v;
        }
        *(float4*)(H2 + gbase + (v << 2)) = h2o;
        *(float4*)(C2 + gbase + (v << 2)) = c2o;
      }
    }
  }
}

extern "C" void kernel_launch(void* const* d_in, const int* in_sizes, int n_in,
                              void* d_out, int out_size, void* d_ws, size_t ws_size,
                              hipStream_t stream) {
  const float* X = (const float*)d_in[0];
  const float* H = (const float*)d_in[1];
  const float* C = (const float*)d_in[2];
  const int* edges = (const int*)d_in[3];     // [2][E]: row0 = src, row1 = dst
  const float* Wlx = (const float*)d_in[4];
  const float* blx = (const float*)d_in[5];
  const float* Wrx = (const float*)d_in[6];
  const float* Wlh = (const float*)d_in[7];
  const float* blh = (const float*)d_in[8];
  const float* Wrh = (const float*)d_in[9];
  const float* wc  = (const float*)d_in[10];
  const float* bg  = (const float*)d_in[11];
  const int N = in_sizes[0] / 128;
  const int E = in_sizes[3] / 2;

  char* ws = (char*)d_ws;
  size_t off = 0;
  auto alloc = [&](size_t bytes) -> void* {
    void* pp = ws + off;
    off = (off + bytes + 511) & ~(size_t)511;
    return pp;
  };
  u32* Abx   = (u32*)alloc((size_t)N * 512);        // [N][256] bf16
  u32* Abh   = (u32*)alloc((size_t)N * 512);
  u16* Btx   = (u16*)alloc(512 * 512);              // fragment-ordered bf16 B
  u16* Bth   = (u16*)alloc(512 * 512);
  int* deg    = (int*)alloc((size_t)N * 4);
  int* rowptr = (int*)alloc(((size_t)N + 1) * 4);
  int* cursor = (int*)alloc((size_t)N * 4);
  int* srcs   = (int*)alloc((size_t)E * 4);

  hipMemsetAsync(deg, 0, (size_t)N * 4, stream);
  k_conv_xh<<<DIV_UP(N * 32, 256), 256, 0, stream>>>((const float4*)X, (const float4*)H, Abx, Abh, N * 32);
  k_hist<<<DIV_UP(E, 256), 256, 0, stream>>>(edges + E, deg, E);
  k_scan<<<1, 1024, 0, stream>>>(deg, rowptr, cursor, N);
  k_scatter<<<DIV_UP(E, 256), 256, 0, stream>>>(edges, edges + E, cursor, srcs, E);
  k_wconv<<<128, 256, 0, stream>>>(Wlx, Wrx, Wlh, Wrh, Btx, Bth);
  k_agg<<<DIV_UP(N * 64, 256), 256, 0, stream>>>(rowptr, srcs, Abx, Abh, N);

  float* H2 = (float*)d_out;
  float* C2 = H2 + (size_t)N * 128;
  k_gemm<<<DIV_UP(N, 64), 512, 0, stream>>>((const u16*)Abx, (const u16*)Abh, Btx, Bth,
                                            blx, blh, wc, bg, C, H2, C2, N);
}